// Round 1
// baseline (208.229 us; speedup 1.0000x reference)
//
#include <hip/hip_runtime.h>

using u16 = unsigned short;
typedef float  f32x4 __attribute__((ext_vector_type(4)));
typedef __bf16 bf8_t __attribute__((ext_vector_type(8)));
typedef u16    u16x4 __attribute__((ext_vector_type(4)));

#define NB 2
#define NH 16
#define NT 2048
#define ND 32
#define NC 512
#define QK_SCALE 0.17677669529663687f   // 1/sqrt(32)

__device__ __forceinline__ u16 f2bf(float f) {
  unsigned int u = __float_as_uint(f);
  u += 0x7fffu + ((u >> 16) & 1u);      // RNE
  return (u16)(u >> 16);
}

__device__ __forceinline__ f32x4 mfma16(bf8_t a, bf8_t b, f32x4 c) {
  return __builtin_amdgcn_mfma_f32_16x16x32_bf16(a, b, c, 0, 0, 0);
}

// ---------------------------------------------------------------------------
// Kernel 1: weights -> bf16 (Wq pre-scaled by 1/sqrt(D)); mask -> float in ws
// and into the mask chunk of d_out (output 1 of the tuple).
// ---------------------------------------------------------------------------
__global__ __launch_bounds__(256) void convert_kernel(
    const float* __restrict__ Wq, const float* __restrict__ Wk,
    const float* __restrict__ Wv, const float* __restrict__ Wp,
    const void* __restrict__ mraw,
    u16* __restrict__ Wc, float* __restrict__ maskf, float* __restrict__ outtail) {
  int bid = blockIdx.x;
  if (bid < 1024) {
    int idx = (bid * 256 + (int)threadIdx.x) * 4;
    int m   = idx >> 18;          // 262144 elements per matrix
    int off = idx & 262143;
    const float* W = (m == 0) ? Wq : (m == 1) ? Wk : (m == 2) ? Wv : Wp;
    float s = (m == 0) ? QK_SCALE : 1.0f;
    f32x4 wv = *(const f32x4*)(W + off);
    u16x4 pk;
    #pragma unroll
    for (int r = 0; r < 4; ++r) pk[r] = f2bf(wv[r] * s);
    *(u16x4*)(Wc + (size_t)m * (NC * NC) + off) = pk;
  } else {
    // mask is (B,1,T) bool. Detect storage: bool-bytes (all-ones -> 0x01010101)
    // vs int32 (all-ones -> 0x00000001). Only read past 4KB if int32 layout.
    unsigned int w0 = *(const unsigned int*)mraw;
    bool intlay = (w0 == 1u);
    #pragma unroll
    for (int kk = 0; kk < 16; ++kk) {
      int j = (int)threadIdx.x + kk * 256;   // 0..4095 = NB*NT
      float mv;
      if (intlay) mv = ((const int*)mraw)[j] ? 1.0f : 0.0f;
      else        mv = ((const unsigned char*)mraw)[j] ? 1.0f : 0.0f;
      maskf[j]   = mv;
      outtail[j] = mv;
    }
  }
}

// ---------------------------------------------------------------------------
// Kernel 2: q/k/v (B,C,T) f32 -> Xt (B,T,C) bf16 (classic LDS tile transpose).
// ---------------------------------------------------------------------------
__global__ __launch_bounds__(256) void transpose_kernel(
    const float* __restrict__ q, const float* __restrict__ k,
    const float* __restrict__ v, u16* __restrict__ Xt) {
  __shared__ float tile[32][33];
  int z = blockIdx.z;
  int m = z >> 1, b = z & 1;
  const float* src = (m == 0) ? q : (m == 1) ? k : v;
  int t0 = blockIdx.x * 32, c0 = blockIdx.y * 32;
  int tx = threadIdx.x, ty = threadIdx.y;
  #pragma unroll
  for (int j = 0; j < 4; ++j)
    tile[ty + j * 8][tx] = src[(size_t)(b * NC + c0 + ty + j * 8) * NT + t0 + tx];
  __syncthreads();
  u16* dst = Xt + (size_t)m * (NB * NT * NC);
  #pragma unroll
  for (int j = 0; j < 4; ++j)
    dst[((size_t)b * NT + t0 + ty + j * 8) * NC + c0 + tx] = f2bf(tile[tx][ty + j * 8]);
}

// ---------------------------------------------------------------------------
// Kernel 3: the 3 input projections. out = W @ X + b.
// A-fragments direct from W (row-major, k-contiguous); B-fragments direct from
// Xt (t rows, c contiguous). Block tile 64(M) x 128(N), 4 waves of 64x32.
// z: 0=Q (-> (B,H,T,D), scaled), 1=K (-> (B,H,T,D)), 2=V (-> (B,C,T), masked).
// ---------------------------------------------------------------------------
__global__ __launch_bounds__(256) void proj_kernel(
    const u16* __restrict__ Wc, const u16* __restrict__ Xt,
    const float* __restrict__ bq, const float* __restrict__ bk, const float* __restrict__ bv,
    u16* __restrict__ Qw, u16* __restrict__ Kw, u16* __restrict__ Vw,
    const float* __restrict__ maskf) {
  int z = blockIdx.z;
  const u16* W = Wc + (size_t)z * (NC * NC);
  const float* bias = (z == 0) ? bq : (z == 1) ? bk : bv;
  int tid = threadIdx.x, wid = tid >> 6, lane = tid & 63;
  int lq = lane & 15, g = lane >> 4;
  int om0 = blockIdx.x * 64;
  int b   = blockIdx.y >> 4;
  int t0  = (blockIdx.y & 15) * 128 + wid * 32;
  const u16* Xb = Xt + (size_t)z * (NB * NT * NC) + (size_t)b * NT * NC;

  const f32x4 zero = {0.f, 0.f, 0.f, 0.f};
  f32x4 acc[4][2];
  #pragma unroll
  for (int mt = 0; mt < 4; ++mt)
    #pragma unroll
    for (int nt = 0; nt < 2; ++nt) acc[mt][nt] = zero;

  for (int ks = 0; ks < 16; ++ks) {       // K = 512, BK = 32
    bf8_t af[4], bfr[2];
    #pragma unroll
    for (int mt = 0; mt < 4; ++mt)
      af[mt] = *(const bf8_t*)(W + (size_t)(om0 + mt * 16 + lq) * NC + ks * 32 + 8 * g);
    #pragma unroll
    for (int nt = 0; nt < 2; ++nt)
      bfr[nt] = *(const bf8_t*)(Xb + (size_t)(t0 + nt * 16 + lq) * NC + ks * 32 + 8 * g);
    #pragma unroll
    for (int mt = 0; mt < 4; ++mt)
      #pragma unroll
      for (int nt = 0; nt < 2; ++nt)
        acc[mt][nt] = mfma16(af[mt], bfr[nt], acc[mt][nt]);
  }

  float sc = (z == 0) ? QK_SCALE : 1.0f;  // W already scaled for Q; scale bias too
  #pragma unroll
  for (int mt = 0; mt < 4; ++mt) {
    int ob = om0 + mt * 16 + 4 * g;       // 4 consecutive output channels (regs)
    float b4[4];
    #pragma unroll
    for (int r = 0; r < 4; ++r) b4[r] = bias[ob + r] * sc;
    #pragma unroll
    for (int nt = 0; nt < 2; ++nt) {
      int t = t0 + nt * 16 + lq;
      if (z < 2) {
        u16x4 pk;
        #pragma unroll
        for (int r = 0; r < 4; ++r) pk[r] = f2bf(acc[mt][nt][r] + b4[r]);
        u16* dst = (z == 0) ? Qw : Kw;
        // (B,H,T,D): 4 consecutive d within one head -> one 8B store
        *(u16x4*)(dst + ((size_t)(b * NH + (ob >> 5)) * NT + t) * ND + (ob & 31)) = pk;
      } else {
        float mv = maskf[b * NT + t];     // vm = vh * mask
        #pragma unroll
        for (int r = 0; r < 4; ++r)
          Vw[(size_t)(b * NC + ob + r) * NT + t] = f2bf((acc[mt][nt][r] + b4[r]) * mv);
      }
    }
  }
}

// ---------------------------------------------------------------------------
// Kernel 4: flash attention. 4 waves/block, each wave owns 32 q-rows of one
// (b,h). Swapped operands: S^T = mfma(K,Q), O^T = mfma(V,P^T) so per-query
// softmax state is lane-local in (lane&15). P bounces through a per-wave
// XOR-swizzled 8KB LDS tile (rows 256B -> byte ^= (row&7)<<4, G4 fix).
// ---------------------------------------------------------------------------
__global__ __launch_bounds__(256) void attn_kernel(
    const u16* __restrict__ Qw, const u16* __restrict__ Kw, const u16* __restrict__ Vw,
    u16* __restrict__ Ow, const float* __restrict__ maskf) {
  __shared__ u16 plds[4][32][128];        // per-wave [tq][tk] bf16, swizzled
  int tid = threadIdx.x, wid = tid >> 6, lane = tid & 63;
  int lq = lane & 15, g = lane >> 4;
  int bh = blockIdx.y, b = bh >> 4, h = bh & 15;
  int q0 = blockIdx.x * 128 + wid * 32;
  const u16* Qb = Qw + (size_t)bh * NT * ND;
  const u16* Kb = Kw + (size_t)bh * NT * ND;
  const u16* Vb = Vw + (size_t)(b * NC + h * ND) * NT;
  const float* mfp = maskf + b * NT;
  char* pbase = (char*)&plds[wid][0][0];

  bf8_t qf[2];                            // Q rows held for whole k-loop
  #pragma unroll
  for (int c = 0; c < 2; ++c)
    qf[c] = *(const bf8_t*)(Qb + (size_t)(q0 + c * 16 + lq) * ND + 8 * g);

  const f32x4 zero = {0.f, 0.f, 0.f, 0.f};
  f32x4 acc[2][2];                        // O^T frags [dt][ctq]
  #pragma unroll
  for (int dt = 0; dt < 2; ++dt)
    #pragma unroll
    for (int c = 0; c < 2; ++c) acc[dt][c] = zero;
  float mrun[2] = {-1e30f, -1e30f}, lrun[2] = {0.f, 0.f};

  for (int kt = 0; kt < 16; ++kt) {       // Tk tiles of 128
    int tkb = kt * 128;
    f32x4 st[8][2];                       // S^T frags [rt_k][ctq]; row=tk, col=tq
    #pragma unroll
    for (int rt = 0; rt < 8; ++rt) {
      bf8_t kf = *(const bf8_t*)(Kb + (size_t)(tkb + rt * 16 + lq) * ND + 8 * g);
      st[rt][0] = mfma16(kf, qf[0], zero);
      st[rt][1] = mfma16(kf, qf[1], zero);
    }
    // key-side mask as additive bias: tk = tkb + rt*16 + 4g + r (S^T row)
    #pragma unroll
    for (int rt = 0; rt < 8; ++rt) {
      f32x4 mb = *(const f32x4*)(mfp + tkb + rt * 16 + 4 * g);
      #pragma unroll
      for (int r = 0; r < 4; ++r) {
        float mbias = (mb[r] - 1.0f) * 1e30f;   // 0 if mask==1, -1e30 if 0
        st[rt][0][r] += mbias;
        st[rt][1][r] += mbias;
      }
    }
    // online softmax per tq (lane-local in lane&15; reduce over 4 g-groups)
    #pragma unroll
    for (int c = 0; c < 2; ++c) {
      float tm = -1e30f;
      #pragma unroll
      for (int rt = 0; rt < 8; ++rt)
        #pragma unroll
        for (int r = 0; r < 4; ++r) tm = fmaxf(tm, st[rt][c][r]);
      tm = fmaxf(tm, __shfl_xor(tm, 16));
      tm = fmaxf(tm, __shfl_xor(tm, 32));
      float mnew = fmaxf(mrun[c], tm);
      float al = __expf(mrun[c] - mnew);
      mrun[c] = mnew;
      float rs = 0.f;
      #pragma unroll
      for (int rt = 0; rt < 8; ++rt)
        #pragma unroll
        for (int r = 0; r < 4; ++r) {
          float p = __expf(st[rt][c][r] - mnew);
          st[rt][c][r] = p;
          rs += p;
        }
      rs += __shfl_xor(rs, 16);
      rs += __shfl_xor(rs, 32);
      lrun[c] = lrun[c] * al + rs;
      acc[0][c] *= al;
      acc[1][c] *= al;
    }
    // P^T -> LDS [tq][tk] bf16, 4 consecutive tk per lane -> 8B writes
    #pragma unroll
    for (int rt = 0; rt < 8; ++rt)
      #pragma unroll
      for (int c = 0; c < 2; ++c) {
        int row = c * 16 + lq;
        u16x4 pk;
        #pragma unroll
        for (int r = 0; r < 4; ++r) pk[r] = f2bf(st[rt][c][r]);
        *(u16x4*)(pbase + row * 256 + ((rt * 32 + 8 * g) ^ ((row & 7) << 4))) = pk;
      }
    // O^T += V * P^T   (A = V direct from (B,C,T); B = P^T from LDS)
    #pragma unroll
    for (int kk = 0; kk < 4; ++kk) {
      bf8_t pf[2];
      #pragma unroll
      for (int c = 0; c < 2; ++c) {
        int row = c * 16 + lq;
        pf[c] = *(const bf8_t*)(pbase + row * 256 + ((kk * 64 + 16 * g) ^ ((row & 7) << 4)));
      }
      #pragma unroll
      for (int dt = 0; dt < 2; ++dt) {
        bf8_t vf = *(const bf8_t*)(Vb + (size_t)(dt * 16 + lq) * NT + tkb + kk * 32 + 8 * g);
        acc[dt][0] = mfma16(vf, pf[0], acc[dt][0]);
        acc[dt][1] = mfma16(vf, pf[1], acc[dt][1]);
      }
    }
  }
  // normalize and store O (B,H,T,D); 4 consecutive d per lane -> 8B stores
  #pragma unroll
  for (int c = 0; c < 2; ++c) {
    float inv = 1.0f / lrun[c];
    int t = q0 + c * 16 + lq;
    #pragma unroll
    for (int dt = 0; dt < 2; ++dt) {
      u16x4 o;
      #pragma unroll
      for (int r = 0; r < 4; ++r) o[r] = f2bf(acc[dt][c][r] * inv);
      *(u16x4*)(Ow + ((size_t)bh * NT + t) * ND + dt * 16 + 4 * g) = o;
    }
  }
}

// ---------------------------------------------------------------------------
// Kernel 5: output projection Wp @ O + bp, times mask, f32 into d_out.
// B-fragments direct from O (B,H,T,D): k-chunk of 8 = contiguous d in head ks.
// ---------------------------------------------------------------------------
__global__ __launch_bounds__(256) void outproj_kernel(
    const u16* __restrict__ Wc, const u16* __restrict__ Ow,
    const float* __restrict__ bp, float* __restrict__ out,
    const float* __restrict__ maskf) {
  const u16* W = Wc + (size_t)3 * NC * NC;
  int tid = threadIdx.x, wid = tid >> 6, lane = tid & 63;
  int lq = lane & 15, g = lane >> 4;
  int om0 = blockIdx.x * 64;
  int b   = blockIdx.y >> 4;
  int t0  = (blockIdx.y & 15) * 128 + wid * 32;
  const u16* Ob = Ow + (size_t)b * NH * NT * ND;

  const f32x4 zero = {0.f, 0.f, 0.f, 0.f};
  f32x4 acc[4][2];
  #pragma unroll
  for (int mt = 0; mt < 4; ++mt)
    #pragma unroll
    for (int nt = 0; nt < 2; ++nt) acc[mt][nt] = zero;

  for (int ks = 0; ks < 16; ++ks) {       // ks == head index; d-block = 8g
    bf8_t af[4], bfr[2];
    #pragma unroll
    for (int mt = 0; mt < 4; ++mt)
      af[mt] = *(const bf8_t*)(W + (size_t)(om0 + mt * 16 + lq) * NC + ks * 32 + 8 * g);
    #pragma unroll
    for (int nt = 0; nt < 2; ++nt)
      bfr[nt] = *(const bf8_t*)(Ob + ((size_t)ks * NT + t0 + nt * 16 + lq) * ND + 8 * g);
    #pragma unroll
    for (int mt = 0; mt < 4; ++mt)
      #pragma unroll
      for (int nt = 0; nt < 2; ++nt)
        acc[mt][nt] = mfma16(af[mt], bfr[nt], acc[mt][nt]);
  }
  #pragma unroll
  for (int mt = 0; mt < 4; ++mt) {
    int ob = om0 + mt * 16 + 4 * g;
    float b4[4];
    #pragma unroll
    for (int r = 0; r < 4; ++r) b4[r] = bp[ob + r];
    #pragma unroll
    for (int nt = 0; nt < 2; ++nt) {
      int t = t0 + nt * 16 + lq;
      float mv = maskf[b * NT + t];
      #pragma unroll
      for (int r = 0; r < 4; ++r)
        out[(size_t)(b * NC + ob + r) * NT + t] = (acc[mt][nt][r] + b4[r]) * mv;
    }
  }
}

// ---------------------------------------------------------------------------
extern "C" void kernel_launch(void* const* d_in, const int* in_sizes, int n_in,
                              void* d_out, int out_size, void* d_ws, size_t ws_size,
                              hipStream_t stream) {
  const float* q  = (const float*)d_in[0];
  const float* k  = (const float*)d_in[1];
  const float* v  = (const float*)d_in[2];
  const void*  mr = d_in[3];
  const float* Wq = (const float*)d_in[4];
  const float* bq = (const float*)d_in[5];
  const float* Wk = (const float*)d_in[6];
  const float* bk = (const float*)d_in[7];
  const float* Wv = (const float*)d_in[8];
  const float* bv = (const float*)d_in[9];
  const float* Wp = (const float*)d_in[10];
  const float* bp = (const float*)d_in[11];
  float* out = (float*)d_out;

  // workspace layout (~30 MB)
  u16* Wc = (u16*)d_ws;                                   // 4 * 512*512 bf16
  u16* Xt = Wc + (size_t)4 * NC * NC;                     // 3 * B*T*C bf16
  u16* Qw = Xt + (size_t)3 * NB * NT * NC;                // B*T*C bf16 (B,H,T,D)
  u16* Kw = Qw + (size_t)NB * NT * NC;
  u16* Vw = Kw + (size_t)NB * NT * NC;                    // (B,C,T)
  u16* Ow = Vw + (size_t)NB * NT * NC;                    // (B,H,T,D)
  float* maskf   = (float*)(Ow + (size_t)NB * NT * NC);   // B*T floats
  float* outtail = out + (size_t)NB * NC * NT;            // mask chunk of d_out

  convert_kernel<<<1025, 256, 0, stream>>>(Wq, Wk, Wv, Wp, mr, Wc, maskf, outtail);
  transpose_kernel<<<dim3(NT / 32, NC / 32, 6), dim3(32, 8), 0, stream>>>(q, k, v, Xt);
  proj_kernel<<<dim3(8, 32, 3), 256, 0, stream>>>(Wc, Xt, bq, bk, bv, Qw, Kw, Vw, maskf);
  attn_kernel<<<dim3(16, 32), 256, 0, stream>>>(Qw, Kw, Vw, Ow, maskf);
  outproj_kernel<<<dim3(8, 32), 256, 0, stream>>>(Wc, Ow, bp, out, maskf);
}

// Round 2
// 203.950 us; speedup vs baseline: 1.0210x; 1.0210x over previous
//
#include <hip/hip_runtime.h>

using u16 = unsigned short;
typedef float  f32x4 __attribute__((ext_vector_type(4)));
typedef __bf16 bf8_t __attribute__((ext_vector_type(8)));
typedef u16    u16x4 __attribute__((ext_vector_type(4)));
typedef unsigned int u32x2 __attribute__((ext_vector_type(2)));

#define NB 2
#define NH 16
#define NT 2048
#define ND 32
#define NC 512
#define QK_SCALE 0.17677669529663687f   // 1/sqrt(32)
#define LOG2E    1.4426950408889634f

__device__ __forceinline__ u16 f2bf(float f) {
  unsigned int u = __float_as_uint(f);
  u += 0x7fffu + ((u >> 16) & 1u);      // RNE
  return (u16)(u >> 16);
}

__device__ __forceinline__ unsigned int cvt_pk_bf16(float a, float b) {
  unsigned int r;
  asm("v_cvt_pk_bf16_f32 %0, %1, %2" : "=v"(r) : "v"(a), "v"(b));
  return r;                             // lo16 = bf16(a), hi16 = bf16(b)
}

__device__ __forceinline__ f32x4 mfma16(bf8_t a, bf8_t b, f32x4 c) {
  return __builtin_amdgcn_mfma_f32_16x16x32_bf16(a, b, c, 0, 0, 0);
}

// ---------------------------------------------------------------------------
// Kernel 1: weights -> bf16 (Wq pre-scaled by log2e/sqrt(D)); mask -> float
// (maskf = 0/1 for V+out masking, maskb = 0/-1e30 additive bias) and the mask
// chunk of d_out (output 1 of the tuple).
// ---------------------------------------------------------------------------
__global__ __launch_bounds__(256) void convert_kernel(
    const float* __restrict__ Wq, const float* __restrict__ Wk,
    const float* __restrict__ Wv, const float* __restrict__ Wp,
    const void* __restrict__ mraw,
    u16* __restrict__ Wc, float* __restrict__ maskf, float* __restrict__ maskb,
    float* __restrict__ outtail) {
  int bid = blockIdx.x;
  if (bid < 1024) {
    int idx = (bid * 256 + (int)threadIdx.x) * 4;
    int m   = idx >> 18;          // 262144 elements per matrix
    int off = idx & 262143;
    const float* W = (m == 0) ? Wq : (m == 1) ? Wk : (m == 2) ? Wv : Wp;
    float s = (m == 0) ? (QK_SCALE * LOG2E) : 1.0f;
    f32x4 wv = *(const f32x4*)(W + off);
    u16x4 pk;
    #pragma unroll
    for (int r = 0; r < 4; ++r) pk[r] = f2bf(wv[r] * s);
    *(u16x4*)(Wc + (size_t)m * (NC * NC) + off) = pk;
  } else {
    // mask is (B,1,T) bool. Detect storage: bool-bytes vs int32.
    unsigned int w0 = *(const unsigned int*)mraw;
    bool intlay = (w0 == 1u);
    #pragma unroll
    for (int kk = 0; kk < 16; ++kk) {
      int j = (int)threadIdx.x + kk * 256;   // 0..4095 = NB*NT
      float mv;
      if (intlay) mv = ((const int*)mraw)[j] ? 1.0f : 0.0f;
      else        mv = ((const unsigned char*)mraw)[j] ? 1.0f : 0.0f;
      maskf[j]   = mv;
      maskb[j]   = (mv - 1.0f) * 1e30f;      // 0 if kept, -1e30 if masked
      outtail[j] = mv;
    }
  }
}

// ---------------------------------------------------------------------------
// Kernel 2: q/k/v (B,C,T) f32 -> Xt (B,T,C) bf16 (classic LDS tile transpose).
// ---------------------------------------------------------------------------
__global__ __launch_bounds__(256) void transpose_kernel(
    const float* __restrict__ q, const float* __restrict__ k,
    const float* __restrict__ v, u16* __restrict__ Xt) {
  __shared__ float tile[32][33];
  int z = blockIdx.z;
  int m = z >> 1, b = z & 1;
  const float* src = (m == 0) ? q : (m == 1) ? k : v;
  int t0 = blockIdx.x * 32, c0 = blockIdx.y * 32;
  int tx = threadIdx.x, ty = threadIdx.y;
  #pragma unroll
  for (int j = 0; j < 4; ++j)
    tile[ty + j * 8][tx] = src[(size_t)(b * NC + c0 + ty + j * 8) * NT + t0 + tx];
  __syncthreads();
  u16* dst = Xt + (size_t)m * (NB * NT * NC);
  #pragma unroll
  for (int j = 0; j < 4; ++j)
    dst[((size_t)b * NT + t0 + ty + j * 8) * NC + c0 + tx] = f2bf(tile[tx][ty + j * 8]);
}

// ---------------------------------------------------------------------------
// Kernel 3: the 3 input projections. out = W @ X + b.
// ---------------------------------------------------------------------------
__global__ __launch_bounds__(256) void proj_kernel(
    const u16* __restrict__ Wc, const u16* __restrict__ Xt,
    const float* __restrict__ bq, const float* __restrict__ bk, const float* __restrict__ bv,
    u16* __restrict__ Qw, u16* __restrict__ Kw, u16* __restrict__ Vw,
    const float* __restrict__ maskf) {
  int z = blockIdx.z;
  const u16* W = Wc + (size_t)z * (NC * NC);
  const float* bias = (z == 0) ? bq : (z == 1) ? bk : bv;
  int tid = threadIdx.x, wid = tid >> 6, lane = tid & 63;
  int lq = lane & 15, g = lane >> 4;
  int om0 = blockIdx.x * 64;
  int b   = blockIdx.y >> 4;
  int t0  = (blockIdx.y & 15) * 128 + wid * 32;
  const u16* Xb = Xt + (size_t)z * (NB * NT * NC) + (size_t)b * NT * NC;

  const f32x4 zero = {0.f, 0.f, 0.f, 0.f};
  f32x4 acc[4][2];
  #pragma unroll
  for (int mt = 0; mt < 4; ++mt)
    #pragma unroll
    for (int nt = 0; nt < 2; ++nt) acc[mt][nt] = zero;

  for (int ks = 0; ks < 16; ++ks) {       // K = 512, BK = 32
    bf8_t af[4], bfr[2];
    #pragma unroll
    for (int mt = 0; mt < 4; ++mt)
      af[mt] = *(const bf8_t*)(W + (size_t)(om0 + mt * 16 + lq) * NC + ks * 32 + 8 * g);
    #pragma unroll
    for (int nt = 0; nt < 2; ++nt)
      bfr[nt] = *(const bf8_t*)(Xb + (size_t)(t0 + nt * 16 + lq) * NC + ks * 32 + 8 * g);
    #pragma unroll
    for (int mt = 0; mt < 4; ++mt)
      #pragma unroll
      for (int nt = 0; nt < 2; ++nt)
        acc[mt][nt] = mfma16(af[mt], bfr[nt], acc[mt][nt]);
  }

  float sc = (z == 0) ? (QK_SCALE * LOG2E) : 1.0f;
  #pragma unroll
  for (int mt = 0; mt < 4; ++mt) {
    int ob = om0 + mt * 16 + 4 * g;       // 4 consecutive output channels (regs)
    float b4[4];
    #pragma unroll
    for (int r = 0; r < 4; ++r) b4[r] = bias[ob + r] * sc;
    #pragma unroll
    for (int nt = 0; nt < 2; ++nt) {
      int t = t0 + nt * 16 + lq;
      if (z < 2) {
        u16x4 pk;
        #pragma unroll
        for (int r = 0; r < 4; ++r) pk[r] = f2bf(acc[mt][nt][r] + b4[r]);
        u16* dst = (z == 0) ? Qw : Kw;
        *(u16x4*)(dst + ((size_t)(b * NH + (ob >> 5)) * NT + t) * ND + (ob & 31)) = pk;
      } else {
        float mv = maskf[b * NT + t];     // vm = vh * mask
        #pragma unroll
        for (int r = 0; r < 4; ++r)
          Vw[(size_t)(b * NC + ob + r) * NT + t] = f2bf((acc[mt][nt][r] + b4[r]) * mv);
      }
    }
  }
}

// ---------------------------------------------------------------------------
// Kernel 4: flash attention, VALU-slimmed.
//  - mask bias rides the QK^T MFMA C-in (zero VALU cost)
//  - scores already in log2 domain (scale*log2e folded into Wq) -> v_exp_f32
//  - row sums via an extra ones-row MFMA into acc[2] (matrix pipe, idle anyway)
//  - P packed with v_cvt_pk_bf16_f32
//  - defer-max (THR=8 in log2 units): rescale only when __any(tm > m+8)
//  - V fragments loaded before softmax so L2 latency hides under exp work
// ---------------------------------------------------------------------------
__global__ __launch_bounds__(256) void attn_kernel(
    const u16* __restrict__ Qw, const u16* __restrict__ Kw, const u16* __restrict__ Vw,
    u16* __restrict__ Ow, const float* __restrict__ maskb) {
  __shared__ u16 plds[4][32][128];        // per-wave [tq][tk] bf16, swizzled
  int tid = threadIdx.x, wid = tid >> 6, lane = tid & 63;
  int lq = lane & 15, g = lane >> 4;
  int bh = blockIdx.y, b = bh >> 4, h = bh & 15;
  int q0 = blockIdx.x * 128 + wid * 32;
  const u16* Qb = Qw + (size_t)bh * NT * ND;
  const u16* Kb = Kw + (size_t)bh * NT * ND;
  const u16* Vb = Vw + (size_t)(b * NC + h * ND) * NT;
  const float* mbp = maskb + b * NT;
  char* pbase = (char*)&plds[wid][0][0];

  bf8_t ones;
  #pragma unroll
  for (int j = 0; j < 8; ++j) ones[j] = (__bf16)1.0f;

  bf8_t qf[2];                            // Q rows held for whole k-loop
  #pragma unroll
  for (int c = 0; c < 2; ++c)
    qf[c] = *(const bf8_t*)(Qb + (size_t)(q0 + c * 16 + lq) * ND + 8 * g);

  const f32x4 zero = {0.f, 0.f, 0.f, 0.f};
  f32x4 acc[3][2];                        // [0..1]=O^T frags, [2]=row-sum
  #pragma unroll
  for (int dt = 0; dt < 3; ++dt)
    #pragma unroll
    for (int c = 0; c < 2; ++c) acc[dt][c] = zero;
  float mrun[2] = {0.f, 0.f};             // defer-max running max (log2 units)

  for (int kt = 0; kt < 16; ++kt) {       // Tk tiles of 128
    int tkb = kt * 128;
    // S^T = K @ Q^T + mask_bias (bias in C-in; row = tk matches bias index)
    f32x4 st[8][2];
    #pragma unroll
    for (int rt = 0; rt < 8; ++rt) {
      f32x4 bias = *(const f32x4*)(mbp + tkb + rt * 16 + 4 * g);
      bf8_t kf = *(const bf8_t*)(Kb + (size_t)(tkb + rt * 16 + lq) * ND + 8 * g);
      st[rt][0] = mfma16(kf, qf[0], bias);
      st[rt][1] = mfma16(kf, qf[1], bias);
    }
    // V fragments for this tile: issue now, consumed after softmax
    bf8_t vf[2][4];
    #pragma unroll
    for (int dt = 0; dt < 2; ++dt)
      #pragma unroll
      for (int kk = 0; kk < 4; ++kk)
        vf[dt][kk] = *(const bf8_t*)(Vb + (size_t)(dt * 16 + lq) * NT + tkb + kk * 32 + 8 * g);

    // online softmax per tq (lane-local in lane&15)
    #pragma unroll
    for (int c = 0; c < 2; ++c) {
      float tm = -1e30f;
      #pragma unroll
      for (int rt = 0; rt < 8; ++rt) {    // max3-shaped tree
        tm = fmaxf(fmaxf(st[rt][c][0], st[rt][c][1]), tm);
        tm = fmaxf(fmaxf(st[rt][c][2], st[rt][c][3]), tm);
      }
      tm = fmaxf(tm, __shfl_xor(tm, 16));
      tm = fmaxf(tm, __shfl_xor(tm, 32));
      if (__any(tm > mrun[c] + 8.0f)) {   // defer-max: rescale rarely
        float mnew = fmaxf(mrun[c], tm);
        float al = __builtin_amdgcn_exp2f(mrun[c] - mnew);
        mrun[c] = mnew;
        acc[0][c] *= al; acc[1][c] *= al; acc[2][c] *= al;
      }
      float nm = -mrun[c];
      int row = c * 16 + lq;
      #pragma unroll
      for (int rt = 0; rt < 8; ++rt) {    // exp2 + pack + LDS write
        float p0 = __builtin_amdgcn_exp2f(st[rt][c][0] + nm);
        float p1 = __builtin_amdgcn_exp2f(st[rt][c][1] + nm);
        float p2 = __builtin_amdgcn_exp2f(st[rt][c][2] + nm);
        float p3 = __builtin_amdgcn_exp2f(st[rt][c][3] + nm);
        u32x2 w;
        w[0] = cvt_pk_bf16(p0, p1);
        w[1] = cvt_pk_bf16(p2, p3);
        *(u32x2*)(pbase + row * 256 + ((rt * 32 + 8 * g) ^ ((row & 7) << 4))) = w;
      }
    }
    // O^T += V @ P^T ; row-sum += ones @ P^T (free on the matrix pipe)
    #pragma unroll
    for (int kk = 0; kk < 4; ++kk) {
      bf8_t pf[2];
      #pragma unroll
      for (int c = 0; c < 2; ++c) {
        int row = c * 16 + lq;
        pf[c] = *(const bf8_t*)(pbase + row * 256 + ((kk * 64 + 16 * g) ^ ((row & 7) << 4)));
      }
      #pragma unroll
      for (int c = 0; c < 2; ++c) {
        acc[0][c] = mfma16(vf[0][kk], pf[c], acc[0][c]);
        acc[1][c] = mfma16(vf[1][kk], pf[c], acc[1][c]);
        acc[2][c] = mfma16(ones,      pf[c], acc[2][c]);
      }
    }
  }
  // normalize and store O (B,H,T,D)
  #pragma unroll
  for (int c = 0; c < 2; ++c) {
    float inv = 1.0f / acc[2][c][0];      // all 4 rows of ones-acc are equal
    int t = q0 + c * 16 + lq;
    #pragma unroll
    for (int dt = 0; dt < 2; ++dt) {
      u32x2 o;
      o[0] = cvt_pk_bf16(acc[dt][c][0] * inv, acc[dt][c][1] * inv);
      o[1] = cvt_pk_bf16(acc[dt][c][2] * inv, acc[dt][c][3] * inv);
      *(u32x2*)(Ow + ((size_t)bh * NT + t) * ND + dt * 16 + 4 * g) = o;
    }
  }
}

// ---------------------------------------------------------------------------
// Kernel 5: output projection Wp @ O + bp, times mask, f32 into d_out.
// ---------------------------------------------------------------------------
__global__ __launch_bounds__(256) void outproj_kernel(
    const u16* __restrict__ Wc, const u16* __restrict__ Ow,
    const float* __restrict__ bp, float* __restrict__ out,
    const float* __restrict__ maskf) {
  const u16* W = Wc + (size_t)3 * NC * NC;
  int tid = threadIdx.x, wid = tid >> 6, lane = tid & 63;
  int lq = lane & 15, g = lane >> 4;
  int om0 = blockIdx.x * 64;
  int b   = blockIdx.y >> 4;
  int t0  = (blockIdx.y & 15) * 128 + wid * 32;
  const u16* Ob = Ow + (size_t)b * NH * NT * ND;

  const f32x4 zero = {0.f, 0.f, 0.f, 0.f};
  f32x4 acc[4][2];
  #pragma unroll
  for (int mt = 0; mt < 4; ++mt)
    #pragma unroll
    for (int nt = 0; nt < 2; ++nt) acc[mt][nt] = zero;

  for (int ks = 0; ks < 16; ++ks) {       // ks == head index; d-block = 8g
    bf8_t af[4], bfr[2];
    #pragma unroll
    for (int mt = 0; mt < 4; ++mt)
      af[mt] = *(const bf8_t*)(W + (size_t)(om0 + mt * 16 + lq) * NC + ks * 32 + 8 * g);
    #pragma unroll
    for (int nt = 0; nt < 2; ++nt)
      bfr[nt] = *(const bf8_t*)(Ob + ((size_t)ks * NT + t0 + nt * 16 + lq) * ND + 8 * g);
    #pragma unroll
    for (int mt = 0; mt < 4; ++mt)
      #pragma unroll
      for (int nt = 0; nt < 2; ++nt)
        acc[mt][nt] = mfma16(af[mt], bfr[nt], acc[mt][nt]);
  }
  #pragma unroll
  for (int mt = 0; mt < 4; ++mt) {
    int ob = om0 + mt * 16 + 4 * g;
    float b4[4];
    #pragma unroll
    for (int r = 0; r < 4; ++r) b4[r] = bp[ob + r];
    #pragma unroll
    for (int nt = 0; nt < 2; ++nt) {
      int t = t0 + nt * 16 + lq;
      float mv = maskf[b * NT + t];
      #pragma unroll
      for (int r = 0; r < 4; ++r)
        out[(size_t)(b * NC + ob + r) * NT + t] = (acc[mt][nt][r] + b4[r]) * mv;
    }
  }
}

// ---------------------------------------------------------------------------
extern "C" void kernel_launch(void* const* d_in, const int* in_sizes, int n_in,
                              void* d_out, int out_size, void* d_ws, size_t ws_size,
                              hipStream_t stream) {
  const float* q  = (const float*)d_in[0];
  const float* k  = (const float*)d_in[1];
  const float* v  = (const float*)d_in[2];
  const void*  mr = d_in[3];
  const float* Wq = (const float*)d_in[4];
  const float* bq = (const float*)d_in[5];
  const float* Wk = (const float*)d_in[6];
  const float* bk = (const float*)d_in[7];
  const float* Wv = (const float*)d_in[8];
  const float* bv = (const float*)d_in[9];
  const float* Wp = (const float*)d_in[10];
  const float* bp = (const float*)d_in[11];
  float* out = (float*)d_out;

  // workspace layout (~30 MB)
  u16* Wc = (u16*)d_ws;                                   // 4 * 512*512 bf16
  u16* Xt = Wc + (size_t)4 * NC * NC;                     // 3 * B*T*C bf16
  u16* Qw = Xt + (size_t)3 * NB * NT * NC;                // B*T*C bf16 (B,H,T,D)
  u16* Kw = Qw + (size_t)NB * NT * NC;
  u16* Vw = Kw + (size_t)NB * NT * NC;                    // (B,C,T)
  u16* Ow = Vw + (size_t)NB * NT * NC;                    // (B,H,T,D)
  float* maskf   = (float*)(Ow + (size_t)NB * NT * NC);   // B*T floats
  float* maskb   = maskf + (size_t)NB * NT;               // B*T floats (bias)
  float* outtail = out + (size_t)NB * NC * NT;            // mask chunk of d_out

  convert_kernel<<<1025, 256, 0, stream>>>(Wq, Wk, Wv, Wp, mr, Wc, maskf, maskb, outtail);
  transpose_kernel<<<dim3(NT / 32, NC / 32, 6), dim3(32, 8), 0, stream>>>(q, k, v, Xt);
  proj_kernel<<<dim3(8, 32, 3), 256, 0, stream>>>(Wc, Xt, bq, bk, bv, Qw, Kw, Vw, maskf);
  attn_kernel<<<dim3(16, 32), 256, 0, stream>>>(Qw, Kw, Vw, Ow, maskb);
  outproj_kernel<<<dim3(8, 32), 256, 0, stream>>>(Wc, Ow, bp, out, maskf);
}